// Round 15
// baseline (725.056 us; speedup 1.0000x reference)
//
#include <hip/hip_runtime.h>
#include <stdint.h>

#define NROWS 16384
#define KDIM  512
#define BM 256          // block rows (4 waves x 64)
#define NCHUNK 32       // 16384 / 512
#define INV_T 14.285714285714286f
#define LOG2E 1.4426950408889634f

typedef __bf16 bf16x8 __attribute__((ext_vector_type(8)));
typedef float  f32x16 __attribute__((ext_vector_type(16)));
typedef unsigned short u16x8 __attribute__((ext_vector_type(8)));

// async global->LDS, 16B/lane; LDS dest = wave-uniform base + lane*16
__device__ __forceinline__ void gload_lds16(const void* gptr, void* lptr) {
    uint32_t loff = (uint32_t)(uintptr_t)lptr;
    loff = __builtin_amdgcn_readfirstlane(loff);
    __builtin_amdgcn_global_load_lds(
        (const uint32_t __attribute__((address_space(1)))*)(uintptr_t)gptr,
        (uint32_t __attribute__((address_space(3)))*)(uintptr_t)loff,
        16, 0, 0);
}

// Fragment-major panel for mfma_32x32x16_bf16 (verified exact R5/R9-R12):
// granule(row r, kh=k/32, q=(k/8)&3) at ((kh*512 + r/32)*2 + (q>>1))*64 + (q&1)*32 + (r&31)
// Frag read = (kh*512+rg)*2048 + ks*1024 + lane*16 : lane-contiguous (global OR LDS).

// ---- kernel 1: L2 normalize + scale + bf16 cast into fragment-major panel ----
__global__ void k_norm(const float* __restrict__ X, char* __restrict__ Y, float scale) {
    const int row  = blockIdx.x * 4 + (threadIdx.x >> 6);
    const int lane = threadIdx.x & 63;
    const float* xr = X + (size_t)row * KDIM + lane * 8;
    float4 a = *(const float4*)xr;
    float4 b = *(const float4*)(xr + 4);
    float ss = a.x*a.x + a.y*a.y + a.z*a.z + a.w*a.w
             + b.x*b.x + b.y*b.y + b.z*b.z + b.w*b.w;
    #pragma unroll
    for (int off = 1; off < 64; off <<= 1) ss += __shfl_xor(ss, off);
    const float s = scale / fmaxf(sqrtf(ss), 1e-12f);
    __bf16 o[8];
    o[0] = (__bf16)(a.x * s); o[1] = (__bf16)(a.y * s);
    o[2] = (__bf16)(a.z * s); o[3] = (__bf16)(a.w * s);
    o[4] = (__bf16)(b.x * s); o[5] = (__bf16)(b.y * s);
    o[6] = (__bf16)(b.z * s); o[7] = (__bf16)(b.w * s);
    const int kh = lane >> 2, q = lane & 3;
    const size_t gr = ((size_t)(kh * 512 + (row >> 5)) * 2 + (q >> 1)) * 64
                    + ((q & 1) << 5) + (row & 31);
    *(u16x8*)(Y + gr * 16) = *(const u16x8*)o;
}

// ---- kernel 2: barrier-free fused GEMM + exp2 + row-sum.
// 4 waves x (64 rows x 128 cols), A from global (6-deep prefetch), B strip in LDS
// (two 64KB half-K buffers), 4 strips/block, 2 barriers per strip only.
__global__ __launch_bounds__(256, 1) void k_gemm(const char* __restrict__ A,
                                                 const char* __restrict__ B,
                                                 float* __restrict__ S_part) {
    __shared__ __align__(16) char L[2 * 65536];   // buf0: kh 0-7, buf1: kh 8-15
    char* Lc = (char*)L;

    const int tid  = threadIdx.x;
    const int lane = tid & 63;
    const int w    = tid >> 6;           // 0..3, wave owns rows brow + w*64
    // XCD supertile swizzle (R9-verified): 2048 blocks
    const int bid  = blockIdx.x;
    const int xcd  = bid & 7;
    const int idx  = bid >> 3;
    const int st   = idx >> 5;
    const int wsub = idx & 31;
    const int sg   = xcd * 8 + st;
    const int bg   = sg & 7, cg = sg >> 3;
    const int brow  = (bg * 8 + (wsub >> 2)) * BM;
    const int chunk = cg * 4 + (wsub & 3);    // 512-col chunk, 4 strips of 128
    const int rbA0 = brow >> 5;

// stage half KH0_ of strip C_'s B (64KB = 8 kh x 8KB) into BUFOFF_
#define STGH(C_, KH0_, BUFOFF_) do {                                          \
        const int rbB_ = chunk * 16 + (C_) * 4;                               \
        _Pragma("unroll") for (int kk_ = 0; kk_ < 8; ++kk_) {                 \
            const char* g_ = B + ((size_t)(((KH0_) + kk_) * 512 + rbB_) * 2048) + tid * 16; \
            char* l_ = Lc + (BUFOFF_) + kk_ * 8192 + tid * 16;                \
            gload_lds16(g_, l_);                                              \
            gload_lds16(g_ + 4096, l_ + 4096);                                \
        }                                                                     \
    } while (0)

#define LOADA(KH0_, T_, S_) do {                                              \
        _Pragma("unroll") for (int m_ = 0; m_ < 2; ++m_)                      \
            aF[S_][m_] = *(const bf16x8*)(A                                   \
                + ((size_t)((((KH0_) + ((T_) >> 1)) * 512 + rbA0 + w * 2 + m_) * 2 \
                            + ((T_) & 1)) << 10) + (lane << 4));              \
    } while (0)

#define READB(T_, BUFOFF_, S_) do {                                           \
        _Pragma("unroll") for (int n_ = 0; n_ < 4; ++n_)                      \
            bF[S_][n_] = *(const bf16x8*)(Lc + (BUFOFF_)                      \
                + (((T_) >> 1) * 8192) + (n_ * 2048)                          \
                + (((T_) & 1) << 10) + (lane << 4));                          \
    } while (0)

// one half-K (16 K-steps of 16): 6-deep A prefetch primed BEFORE the stage issue
#define HALF(KH0_, BUFOFF_, STG_STMT_) do {                                   \
        LOADA(KH0_, 0, 0); LOADA(KH0_, 1, 1); LOADA(KH0_, 2, 2);              \
        LOADA(KH0_, 3, 3); LOADA(KH0_, 4, 4); LOADA(KH0_, 5, 5);              \
        STG_STMT_;                                                            \
        READB(0, BUFOFF_, 0);                                                 \
        _Pragma("unroll") for (int tt_ = 0; tt_ < 16; ++tt_) {                \
            if (tt_ < 15) READB(tt_ + 1, BUFOFF_, (tt_ + 1) & 1);             \
            if (tt_ < 10) LOADA(KH0_, tt_ + 6, (tt_ + 6) % 6);                \
            _Pragma("unroll") for (int m_ = 0; m_ < 2; ++m_)                  \
            _Pragma("unroll") for (int n_ = 0; n_ < 4; ++n_)                  \
                acc[m_][n_] = __builtin_amdgcn_mfma_f32_32x32x16_bf16(        \
                    aF[tt_ % 6][m_], bF[tt_ & 1][n_], acc[m_][n_], 0, 0, 0);  \
        }                                                                     \
    } while (0)

    bf16x8 aF[6][2], bF[2][4];
    float rowacc[2][16] = {};

    // prologue: stage strip0 half0 into buf0
    STGH(0, 0, 0);
    asm volatile("s_waitcnt vmcnt(0)" ::: "memory");
    __builtin_amdgcn_s_barrier();

    #pragma unroll 1
    for (int c = 0; c < 4; ++c) {
        f32x16 acc[2][4] = {};
        // half0 (kh 0-7, buf0); stage this strip's half1 into buf1
        HALF(0, 0, STGH(c, 8, 65536));
        asm volatile("s_waitcnt vmcnt(0)" ::: "memory");
        __builtin_amdgcn_s_barrier();
        // half1 (kh 8-15, buf1); stage next strip's half0 into buf0
        if (c < 3) { HALF(8, 65536, STGH(c + 1, 0, 0)); }
        else       { HALF(8, 65536, ((void)0)); }

        // per-strip epilogue: exp2 + in-wave 32-lane row reduce (no LDS, no sync)
        // C/D 32x32: col=lane&31, row = (r&3)+8*(r>>2)+4*(lane>>5)
        #pragma unroll
        for (int m = 0; m < 2; ++m) {
            float rs[16];
            #pragma unroll
            for (int r = 0; r < 16; ++r)
                rs[r] = __builtin_amdgcn_exp2f(acc[m][0][r])
                      + __builtin_amdgcn_exp2f(acc[m][1][r])
                      + __builtin_amdgcn_exp2f(acc[m][2][r])
                      + __builtin_amdgcn_exp2f(acc[m][3][r]);
            #pragma unroll
            for (int off = 16; off >= 1; off >>= 1)
                #pragma unroll
                for (int r = 0; r < 16; ++r)
                    rs[r] += __shfl_xor(rs[r], off);
            #pragma unroll
            for (int r = 0; r < 16; ++r) rowacc[m][r] += rs[r];
        }
        asm volatile("s_waitcnt vmcnt(0)" ::: "memory");
        __builtin_amdgcn_s_barrier();
    }
#undef STGH
#undef LOADA
#undef READB
#undef HALF

    if ((lane & 31) == 0) {
        const int hi = lane >> 5;
        #pragma unroll
        for (int m = 0; m < 2; ++m)
            #pragma unroll
            for (int r = 0; r < 16; ++r)
                S_part[(size_t)chunk * NROWS + brow + w * 64 + m * 32
                       + hi * 4 + (r & 3) + 8 * (r >> 2)] = rowacc[m][r];
    }
}

// ---- kernel 3: diagonal logits in fp32 from RAW inputs (natural units) ----
__global__ void k_diag(const float* __restrict__ X1, const float* __restrict__ X2,
                       float* __restrict__ diag) {
    const int row  = blockIdx.x * 4 + (threadIdx.x >> 6);
    const int lane = threadIdx.x & 63;
    const float* x1 = X1 + (size_t)row * KDIM + lane * 8;
    const float* x2 = X2 + (size_t)row * KDIM + lane * 8;
    float4 a0 = *(const float4*)x1, a1 = *(const float4*)(x1 + 4);
    float4 b0 = *(const float4*)x2, b1 = *(const float4*)(x2 + 4);
    float s1 = a0.x*a0.x + a0.y*a0.y + a0.z*a0.z + a0.w*a0.w
             + a1.x*a1.x + a1.y*a1.y + a1.z*a1.z + a1.w*a1.w;
    float s2 = b0.x*b0.x + b0.y*b0.y + b0.z*b0.z + b0.w*b0.w
             + b1.x*b1.x + b1.y*b1.y + b1.z*b1.z + b1.w*b1.w;
    float dd = a0.x*b0.x + a0.y*b0.y + a0.z*b0.z + a0.w*b0.w
             + a1.x*b1.x + a1.y*b1.y + a1.z*b1.z + a1.w*b1.w;
    #pragma unroll
    for (int off = 1; off < 64; off <<= 1) {
        s1 += __shfl_xor(s1, off);
        s2 += __shfl_xor(s2, off);
        dd += __shfl_xor(dd, off);
    }
    if (lane == 0)
        diag[row] = dd / (fmaxf(sqrtf(s1), 1e-12f) * fmaxf(sqrtf(s2), 1e-12f)) * INV_T;
}

// ---- kernel 4: per-row loss + deterministic block partials ----
__global__ void k_loss(const float* __restrict__ S_part, const float* __restrict__ diag,
                       float* __restrict__ partial) {
    const int g = blockIdx.x * 256 + threadIdx.x;
    float S = 0.f;
    #pragma unroll
    for (int c = 0; c < NCHUNK; ++c) S += S_part[(size_t)c * NROWS + g];
    float v = logf(S) - diag[g];
    __shared__ float wsum[4];
    #pragma unroll
    for (int off = 1; off < 64; off <<= 1) v += __shfl_xor(v, off);
    if ((threadIdx.x & 63) == 0) wsum[threadIdx.x >> 6] = v;
    __syncthreads();
    if (threadIdx.x == 0) partial[blockIdx.x] = wsum[0] + wsum[1] + wsum[2] + wsum[3];
}

__global__ void k_final(const float* __restrict__ partial, float* __restrict__ out) {
    float v = partial[threadIdx.x];
    #pragma unroll
    for (int off = 1; off < 64; off <<= 1) v += __shfl_xor(v, off);
    if (threadIdx.x == 0) out[0] = v * (1.0f / (float)NROWS);
}

extern "C" void kernel_launch(void* const* d_in, const int* in_sizes, int n_in,
                              void* d_out, int out_size, void* d_ws, size_t ws_size,
                              hipStream_t stream) {
    const float* f1 = (const float*)d_in[0];
    const float* f2 = (const float*)d_in[1];
    float* out = (float*)d_out;

    char* ws = (char*)d_ws;
    char*  f1p   = ws;                                  // 16 MB panel (log2-scaled by 1/T)
    char*  f2p   = ws + (16u << 20);                    // 16 MB panel
    float* S_part = (float*)(ws + (32u << 20));         // 2 MB [NCHUNK][NROWS]
    float* diag   = (float*)(ws + (34u << 20));         // 64 KB
    float* part   = (float*)(ws + (34u << 20) + (1u << 16)); // 256 B

    k_norm<<<dim3(NROWS / 4), dim3(256), 0, stream>>>(f1, f1p, INV_T * LOG2E);
    k_norm<<<dim3(NROWS / 4), dim3(256), 0, stream>>>(f2, f2p, 1.0f);
    // 2048 blocks: 64 row-blocks x 32 chunks (block: 256 rows x 512 cols via 4 strips)
    k_gemm<<<dim3((NROWS / BM) * NCHUNK), dim3(256), 0, stream>>>(f1p, f2p, S_part);
    k_diag<<<dim3(NROWS / 4), dim3(256), 0, stream>>>(f1, f2, diag);
    k_loss<<<dim3(NROWS / 256), dim3(256), 0, stream>>>(S_part, diag, part);
    k_final<<<dim3(1), dim3(64), 0, stream>>>(part, out);
}

// Round 16
// 354.430 us; speedup vs baseline: 2.0457x; 2.0457x over previous
//
#include <hip/hip_runtime.h>
#include <stdint.h>

#define NROWS 16384
#define KDIM  512
#define BM 128          // block rows
#define BN 128          // per-ct column strip
#define CT 4            // strips per block -> 512-col chunk
#define NCHUNK 32       // 16384 / 512
#define NPH 16          // K-halves of 32: 512/32
#define SLOT 16384      // A 8KB + B 8KB
#define INV_T 14.285714285714286f
#define LOG2E 1.4426950408889634f

typedef __bf16 bf16x8 __attribute__((ext_vector_type(8)));
typedef float  f32x16 __attribute__((ext_vector_type(16)));
typedef unsigned short u16x8 __attribute__((ext_vector_type(8)));

// async global->LDS, 16B/lane; LDS dest = wave-uniform base + lane*16
__device__ __forceinline__ void gload_lds16(const void* gptr, void* lptr) {
    uint32_t loff = (uint32_t)(uintptr_t)lptr;
    loff = __builtin_amdgcn_readfirstlane(loff);
    __builtin_amdgcn_global_load_lds(
        (const uint32_t __attribute__((address_space(1)))*)(uintptr_t)gptr,
        (uint32_t __attribute__((address_space(3)))*)(uintptr_t)loff,
        16, 0, 0);
}

// Fragment-major panel for mfma_32x32x16_bf16 (verified exact R5/R9-R12):
// granule(row r, kh=k/32, q=(k/8)&3) at ((kh*512 + r/32)*2 + (q>>1))*64 + (q&1)*32 + (r&31)
// Wave frag read = Rgroup*2048 + ks*1024 + lane*16 : lane-contiguous, conflict-free.

// ---- kernel 1: L2 normalize + scale + bf16 cast into fragment-major panel ----
__global__ void k_norm(const float* __restrict__ X, char* __restrict__ Y, float scale) {
    const int row  = blockIdx.x * 4 + (threadIdx.x >> 6);
    const int lane = threadIdx.x & 63;
    const float* xr = X + (size_t)row * KDIM + lane * 8;
    float4 a = *(const float4*)xr;
    float4 b = *(const float4*)(xr + 4);
    float ss = a.x*a.x + a.y*a.y + a.z*a.z + a.w*a.w
             + b.x*b.x + b.y*b.y + b.z*b.z + b.w*b.w;
    #pragma unroll
    for (int off = 1; off < 64; off <<= 1) ss += __shfl_xor(ss, off);
    const float s = scale / fmaxf(sqrtf(ss), 1e-12f);
    __bf16 o[8];
    o[0] = (__bf16)(a.x * s); o[1] = (__bf16)(a.y * s);
    o[2] = (__bf16)(a.z * s); o[3] = (__bf16)(a.w * s);
    o[4] = (__bf16)(b.x * s); o[5] = (__bf16)(b.y * s);
    o[6] = (__bf16)(b.z * s); o[7] = (__bf16)(b.w * s);
    const int kh = lane >> 2, q = lane & 3;
    const size_t gr = ((size_t)(kh * 512 + (row >> 5)) * 2 + (q >> 1)) * 64
                    + ((q & 1) << 5) + (row & 31);
    *(u16x8*)(Y + gr * 16) = *(const u16x8*)o;
}

// ---- kernel 2: fused GEMM + exp2 + row-sum. 128x128 per step, 4 waves (2Mx2N),
// wave tile 64x64, acc[2][2] (64f, spill-free), ring-3 16KB slots, 49KB LDS ->
// 2 INDEPENDENT blocks/CU (no shared barrier domain -> MFMA/LDS overlap).
__global__ __launch_bounds__(256, 2) void k_gemm(const char* __restrict__ A,
                                                 const char* __restrict__ B,
                                                 float* __restrict__ S_part) {
    __shared__ __align__(16) char L[3 * SLOT];    // 48KB
    __shared__ float rowsum[2][BM];               // 1KB
    char* Lc = (char*)L;

    const int tid  = threadIdx.x;
    const int lane = tid & 63;
    const int w    = tid >> 6;           // 0..3
    const int wr   = w >> 1, wc = w & 1; // 2M x 2N; wave tile 64x64
    // XCD swizzle (R11-verified, 4096 blocks): per XCD 16 supertiles of (8 brow x 4 chunk)
    const int bid  = blockIdx.x;
    const int xcd  = bid & 7;
    const int idx  = bid >> 3;           // 0..511
    const int st   = idx >> 5;           // 0..15
    const int wsub = idx & 31;
    const int sg   = xcd * 16 + st;      // 0..127
    const int bg   = sg & 15, cg = sg >> 4;
    const int brow  = (bg * 8 + (wsub >> 2)) * BM;   // 0..127 * 128
    const int chunk = cg * 4 + (wsub & 3);           // 0..31, 512-col chunk
    const int rbA0 = brow >> 5;          // 4 Rgroups of A

#define STGA(KH_, S_) do {                                                    \
        const char* g_ = A + ((size_t)((KH_) * 512 + rbA0) * 2048) + tid * 16;\
        char* l_ = Lc + (S_) * SLOT + tid * 16;                               \
        gload_lds16(g_,        l_);                                           \
        gload_lds16(g_ + 4096, l_ + 4096);                                    \
    } while (0)

#define STGB(KH_, S_) do {                                                    \
        const char* g_ = B + ((size_t)((KH_) * 512 + rbB0) * 2048) + tid * 16;\
        char* l_ = Lc + (S_) * SLOT + 8192 + tid * 16;                        \
        gload_lds16(g_,        l_);                                           \
        gload_lds16(g_ + 4096, l_ + 4096);                                    \
    } while (0)

// read frags of K-half HH_ from slot (HH_%3)
#define RDS(HH_) do {                                                         \
        const char* sl_ = Lc + ((HH_) % 3) * SLOT;                            \
        _Pragma("unroll") for (int m_ = 0; m_ < 2; ++m_)                      \
        _Pragma("unroll") for (int ks_ = 0; ks_ < 2; ++ks_)                   \
            af[m_][ks_] = *(const bf16x8*)(sl_ + ((wr * 2 + m_) << 11)        \
                                           + (ks_ << 10) + (lane << 4));      \
        _Pragma("unroll") for (int n_ = 0; n_ < 2; ++n_)                      \
        _Pragma("unroll") for (int ks_ = 0; ks_ < 2; ++ks_)                   \
            bf[n_][ks_] = *(const bf16x8*)(sl_ + 8192 + ((wc * 2 + n_) << 11) \
                                           + (ks_ << 10) + (lane << 4));      \
    } while (0)

#define MM() do {                                                             \
        __builtin_amdgcn_s_setprio(1);                                        \
        _Pragma("unroll") for (int m_ = 0; m_ < 2; ++m_)                      \
        _Pragma("unroll") for (int n_ = 0; n_ < 2; ++n_)                      \
        _Pragma("unroll") for (int ks_ = 0; ks_ < 2; ++ks_)                   \
            acc[m_][n_] = __builtin_amdgcn_mfma_f32_32x32x16_bf16(            \
                af[m_][ks_], bf[n_][ks_], acc[m_][n_], 0, 0, 0);              \
        __builtin_amdgcn_s_setprio(0);                                        \
    } while (0)

    float rowacc = 0.f;
    #pragma unroll 1
    for (int ct = 0; ct < CT; ++ct) {
        const int rbB0 = chunk * 16 + ct * 4;   // 4 Rgroups of B (128 cols)
        f32x16 acc[2][2] = {};
        bf16x8 af[2][2], bf[2][2];

        // prologue: stage H0->slot0, H1->slot1 (4 loads each); wait H0
        STGA(0, 0); STGB(0, 0);
        STGA(1, 1); STGB(1, 1);
        asm volatile("s_waitcnt vmcnt(4)" ::: "memory");
        __builtin_amdgcn_s_barrier();

        #pragma unroll
        for (int h = 0; h < NPH; ++h) {
            RDS(h);
            if (h < NPH - 2) { STGA(h + 2, (h + 2) % 3); STGB(h + 2, (h + 2) % 3); }
            MM();
            // invariant: entering phase h+1, H(h+1) landed (its 4 loads drained)
            if (h < NPH - 2)       asm volatile("s_waitcnt vmcnt(4)" ::: "memory");
            else if (h == NPH - 2) asm volatile("s_waitcnt vmcnt(0)" ::: "memory");
            __builtin_amdgcn_s_barrier();
        }

        // epilogue: C/D 32x32: col=lane&31, row=(r&3)+8*(r>>2)+4*(lane>>5)
        #pragma unroll
        for (int m = 0; m < 2; ++m) {
            float rs[16];
            #pragma unroll
            for (int r = 0; r < 16; ++r)
                rs[r] = __builtin_amdgcn_exp2f(acc[m][0][r])
                      + __builtin_amdgcn_exp2f(acc[m][1][r]);
            #pragma unroll
            for (int off = 16; off >= 1; off >>= 1)
                #pragma unroll
                for (int r = 0; r < 16; ++r)
                    rs[r] += __shfl_xor(rs[r], off);
            if ((lane & 31) == 0) {
                const int rb = wr * 64 + m * 32 + (lane >> 5) * 4;
                #pragma unroll
                for (int r = 0; r < 16; ++r)
                    rowsum[wc][rb + (r & 3) + 8 * (r >> 2)] = rs[r];
            }
        }
        __syncthreads();
        if (tid < BM) rowacc += rowsum[0][tid] + rowsum[1][tid];
        __syncthreads();
    }
#undef STGA
#undef STGB
#undef RDS
#undef MM
    if (tid < BM) S_part[(size_t)chunk * NROWS + brow + tid] = rowacc;
}

// ---- kernel 3: diagonal logits in fp32 from RAW inputs (natural units) ----
__global__ void k_diag(const float* __restrict__ X1, const float* __restrict__ X2,
                       float* __restrict__ diag) {
    const int row  = blockIdx.x * 4 + (threadIdx.x >> 6);
    const int lane = threadIdx.x & 63;
    const float* x1 = X1 + (size_t)row * KDIM + lane * 8;
    const float* x2 = X2 + (size_t)row * KDIM + lane * 8;
    float4 a0 = *(const float4*)x1, a1 = *(const float4*)(x1 + 4);
    float4 b0 = *(const float4*)x2, b1 = *(const float4*)(x2 + 4);
    float s1 = a0.x*a0.x + a0.y*a0.y + a0.z*a0.z + a0.w*a0.w
             + a1.x*a1.x + a1.y*a1.y + a1.z*a1.z + a1.w*a1.w;
    float s2 = b0.x*b0.x + b0.y*b0.y + b0.z*b0.z + b0.w*b0.w
             + b1.x*b1.x + b1.y*b1.y + b1.z*b1.z + b1.w*b1.w;
    float dd = a0.x*b0.x + a0.y*b0.y + a0.z*b0.z + a0.w*b0.w
             + a1.x*b1.x + a1.y*b1.y + a1.z*b1.z + a1.w*b1.w;
    #pragma unroll
    for (int off = 1; off < 64; off <<= 1) {
        s1 += __shfl_xor(s1, off);
        s2 += __shfl_xor(s2, off);
        dd += __shfl_xor(dd, off);
    }
    if (lane == 0)
        diag[row] = dd / (fmaxf(sqrtf(s1), 1e-12f) * fmaxf(sqrtf(s2), 1e-12f)) * INV_T;
}

// ---- kernel 4: per-row loss + deterministic block partials ----
__global__ void k_loss(const float* __restrict__ S_part, const float* __restrict__ diag,
                       float* __restrict__ partial) {
    const int g = blockIdx.x * 256 + threadIdx.x;
    float S = 0.f;
    #pragma unroll
    for (int c = 0; c < NCHUNK; ++c) S += S_part[(size_t)c * NROWS + g];
    float v = logf(S) - diag[g];
    __shared__ float wsum[4];
    #pragma unroll
    for (int off = 1; off < 64; off <<= 1) v += __shfl_xor(v, off);
    if ((threadIdx.x & 63) == 0) wsum[threadIdx.x >> 6] = v;
    __syncthreads();
    if (threadIdx.x == 0) partial[blockIdx.x] = wsum[0] + wsum[1] + wsum[2] + wsum[3];
}

__global__ void k_final(const float* __restrict__ partial, float* __restrict__ out) {
    float v = partial[threadIdx.x];
    #pragma unroll
    for (int off = 1; off < 64; off <<= 1) v += __shfl_xor(v, off);
    if (threadIdx.x == 0) out[0] = v * (1.0f / (float)NROWS);
}

extern "C" void kernel_launch(void* const* d_in, const int* in_sizes, int n_in,
                              void* d_out, int out_size, void* d_ws, size_t ws_size,
                              hipStream_t stream) {
    const float* f1 = (const float*)d_in[0];
    const float* f2 = (const float*)d_in[1];
    float* out = (float*)d_out;

    char* ws = (char*)d_ws;
    char*  f1p   = ws;                                  // 16 MB panel (log2/T-scaled)
    char*  f2p   = ws + (16u << 20);                    // 16 MB panel
    float* S_part = (float*)(ws + (32u << 20));         // 2 MB [NCHUNK][NROWS]
    float* diag   = (float*)(ws + (34u << 20));         // 64 KB
    float* part   = (float*)(ws + (34u << 20) + (1u << 16)); // 256 B

    k_norm<<<dim3(NROWS / 4), dim3(256), 0, stream>>>(f1, f1p, INV_T * LOG2E);
    k_norm<<<dim3(NROWS / 4), dim3(256), 0, stream>>>(f2, f2p, 1.0f);
    // 4096 blocks: 128 brow x 32 chunk (block: 128 rows x 512 cols via CT=4)
    k_gemm<<<dim3((NROWS / BM) * NCHUNK), dim3(256), 0, stream>>>(f1p, f2p, S_part);
    k_diag<<<dim3(NROWS / 4), dim3(256), 0, stream>>>(f1, f2, diag);
    k_loss<<<dim3(NROWS / 256), dim3(256), 0, stream>>>(S_part, diag, part);
    k_final<<<dim3(1), dim3(64), 0, stream>>>(part, out);
}